// Round 11
// baseline (167.934 us; speedup 1.0000x reference)
//
#include <hip/hip_runtime.h>
#include <math.h>

// VQ-VAE vector quantizer for MI355X.
// z: [32, 64, 64, 64] fp32 (B, C=D, H, W), embedding: [1024, 64] fp32.
// Outputs (concatenated fp32 in d_out):
//   [0 .. 8388607]  quantized, layout (b, c, h, w)
//   [8388608]       loss = L + 0.25*L, L = mean((q - z)^2)
//   [8388609]       perplexity
//   [8388610 .. ]   encoding indices (as float), 131072 of them
//
// Round 11: ONE WAVE PER BLOCK. r8/r10 showed an invariant ~87us stall under
// halved work and doubled occupancy -> the 4-wave barrier'd phase chain
// (several phases using 64/256 threads) serialized everything in lockstep.
// Now: 64-thread blocks, 2048 blocks; each wave owns all 64 rows x 1024
// codes. All phases wave-internal; sweep-1 min is globally settled before
// collect. ee read from global (L1-resident); LDS ~20KB -> 8 blocks/CU
// resident == all work resident, zero tail. Depth-2 prefetch, 4 rotating
// buffers with static (&3) indices. Exact-rescore chain unchanged
// (reference-bit-exact; validated rounds 7-10, absmax 3.8e-6).

#define NROWS 131072
#define KCODES 1024
#define DDIM 64
#define CAP 16

typedef __attribute__((ext_vector_type(8))) short short8v;  // 8 bf16
typedef __attribute__((ext_vector_type(4))) float f32x4;

// Prevent fp contraction (hipcc defaults to -ffp-contract=fast).
__device__ __forceinline__ float nofuse(float x) {
    asm("" : "+v"(x));
    return x;
}

// numpy pairwise_sum for n=64 of terms a[i]*a[i] (8-stripe + fixed tree).
template <typename F>
__device__ __forceinline__ float pairwise64_sq(F load) {
    float r[8];
#pragma unroll
    for (int j = 0; j < 8; j++) {
        float v = load(j);
        r[j] = nofuse(v * v);
    }
#pragma unroll
    for (int i = 8; i < 64; i += 8) {
#pragma unroll
        for (int j = 0; j < 8; j++) {
            float v = load(i + j);
            r[j] = r[j] + nofuse(v * v);
        }
    }
    return ((r[0] + r[1]) + (r[2] + r[3])) + ((r[4] + r[5]) + (r[6] + r[7]));
}

__device__ __forceinline__ unsigned short bf16_rne(float x) {
    unsigned u = __float_as_uint(x);
    u += 0x7FFFu + ((u >> 16) & 1u);
    return (unsigned short)(u >> 16);
}

// --- kernel E: ee[k] (numpy-pairwise exact) + eh bf16 pack ---
__global__ __launch_bounds__(256) void kE(const float* __restrict__ emb,
                                          float* __restrict__ ee,
                                          unsigned short* __restrict__ eh_p) {
    int k = blockIdx.x * 256 + threadIdx.x;
    if (k >= KCODES) return;
    const float* er = emb + (size_t)k * DDIM;
    ee[k] = pairwise64_sq([&](int i) { return er[i]; });
#pragma unroll
    for (int i = 0; i < DDIM; i++) eh_p[(size_t)k * DDIM + i] = bf16_rne(er[i]);
}

#define MFMA_BF16(acc, a, b) \
    acc = __builtin_amdgcn_mfma_f32_16x16x32_bf16(a, b, acc, 0, 0, 0)

// 8 MFMAs (4 row-tiles x K=64, hi-only) for one 16-code tile, then ACT.
// Identical arithmetic in sweep 1 and sweep 2 -> bit-identical s~ values.
#define DOT_TILE(ti, B0, B1, ACT)                                       \
    {                                                                   \
        const int codeL = (ti) * 16 + (l & 15);                         \
        const float eev = ee[codeL];                                    \
        _Pragma("unroll") for (int rt = 0; rt < 4; rt++) {              \
            f32x4 acc = {0.f, 0.f, 0.f, 0.f};                           \
            MFMA_BF16(acc, ah[rt][0], B0);                              \
            MFMA_BF16(acc, ah[rt][1], B1);                              \
            _Pragma("unroll") for (int r = 0; r < 4; r++) {             \
                float sv = fmaf(-2.0f, acc[r], eev);                    \
                ACT(rt, r, sv, codeL);                                  \
            }                                                           \
        }                                                               \
    }

#define ACT_MIN(rt, r, sv, code) rm[rt][r] = fminf(rm[rt][r], sv);
#define ACT_COLLECT(rt, r, sv, code)                                    \
    if (sv <= thr_r[rt][r]) {                                           \
        int row_ = rt * 16 + ((l >> 4) << 2) + r;                       \
        int pos_ = atomicAdd(&cnt_s[row_], 1);                          \
        if (pos_ < CAP) cand_s[row_][pos_] = (unsigned short)(code);    \
    }

#define PRE_B(ti)                                                       \
    {                                                                   \
        const unsigned short* p_ =                                      \
            eh_p + (size_t)((ti) * 16 + (l & 15)) * 64 + kg;            \
        pb0[(ti) & 3] = *(const short8v*)p_;                            \
        pb1[(ti) & 3] = *(const short8v*)(p_ + 32);                     \
    }

// --- kernel A2: 1 wave/block. MFMA filter + exact rescore + fused outputs.
// Block: 64 threads, 64 rows = one (b,h), all 1024 codes.
// MFMA 16x16x32 bf16: A[m][k]: m=lane&15, k=(lane>>4)*8+i; B[k][n]:
// n=lane&15, same k; D[m][n]: n=lane&15, m=(lane>>4)*4+reg (m89-verified).
__global__ __launch_bounds__(64) void kA2(
    const float* __restrict__ z, const float* __restrict__ emb,
    const float* __restrict__ ee, const unsigned short* __restrict__ eh_p,
    int* __restrict__ counts, float* __restrict__ out_idx,
    float* __restrict__ out_q, double* __restrict__ loss_sum) {
    __shared__ float zt[64][65];       // [w][d]
    __shared__ float zz_s[64];
    __shared__ float wq_s[64];         // per-row window W_row
    __shared__ float thr_s[64];        // per-row threshold (min + W)
    __shared__ int cnt_s[64];
    __shared__ unsigned short cand_s[64][CAP];

    const int l = threadIdx.x;         // lane 0..63
    const int blk = blockIdx.x;        // 0..2047
    const int n0 = blk * 64;
    const int b = blk >> 6;
    const int h = blk & 63;
    const int kg = (l >> 4) * 8;       // k-slice base within 32-wide half

    // ---- stage z tile (float4 coalesced), transpose into LDS ----
    const float* zb = z + (size_t)b * 262144 + (size_t)h * 64;
#pragma unroll
    for (int it = 0; it < 16; it++) {
        int idx = it * 64 + l;
        int d = idx >> 4, w4 = (idx & 15) * 4;
        float4 v = *(const float4*)(zb + (size_t)d * 4096 + w4);
        zt[w4 + 0][d] = v.x;
        zt[w4 + 1][d] = v.y;
        zt[w4 + 2][d] = v.z;
        zt[w4 + 3][d] = v.w;
    }
    __syncthreads();

    // ---- per-row zz (exact pairwise) + window; lane w == row w ----
    const float zz = pairwise64_sq([&](int i) { return zt[l][i]; });
    zz_s[l] = zz;
    {
        float sa[8];
#pragma unroll
        for (int j = 0; j < 8; j++) sa[j] = fabsf(zt[l][j]);
#pragma unroll
        for (int i = 8; i < 64; i += 8)
#pragma unroll
            for (int j = 0; j < 8; j++) sa[j] += fabsf(zt[l][i + j]);
        float s = ((sa[0] + sa[1]) + (sa[2] + sa[3])) +
                  ((sa[4] + sa[5]) + (sa[6] + sa[7]));
        wq_s[l] = fmaf(2e-5f, s, 1e-4f);  // hi-only bound, >=2.6x margin
    }
    cnt_s[l] = 0;
    __syncthreads();

    // ---- A fragments (hi bf16 only) for all 64 rows = 4 row-tiles ----
    short8v ah[4][2];
#pragma unroll
    for (int rt = 0; rt < 4; rt++) {
        const int arow = rt * 16 + (l & 15);
#pragma unroll
        for (int kt = 0; kt < 2; kt++) {
#pragma unroll
            for (int i = 0; i < 8; i++)
                ah[rt][kt][i] = (short)bf16_rne(zt[arow][kt * 32 + kg + i]);
        }
    }

    // ---- sweep 1: per-row approx min over ALL 1024 codes ----
    float rm[4][4];
#pragma unroll
    for (int rt = 0; rt < 4; rt++)
#pragma unroll
        for (int r = 0; r < 4; r++) rm[rt][r] = INFINITY;
    {
        short8v pb0[4], pb1[4];
        PRE_B(0)
        PRE_B(1)
#pragma unroll 4
        for (int ti = 0; ti < 64; ti++) {
            if (ti < 62) PRE_B(ti + 2)
            DOT_TILE(ti, pb0[ti & 3], pb1[ti & 3], ACT_MIN)
        }
    }
    // reduce min across the 16 code-lanes in each lane group
#pragma unroll
    for (int rt = 0; rt < 4; rt++)
#pragma unroll
        for (int r = 0; r < 4; r++) {
            float v = rm[rt][r];
            v = fminf(v, __shfl_xor(v, 1, 64));
            v = fminf(v, __shfl_xor(v, 2, 64));
            v = fminf(v, __shfl_xor(v, 4, 64));
            v = fminf(v, __shfl_xor(v, 8, 64));
            rm[rt][r] = v;
        }
    if ((l & 15) == 0) {
#pragma unroll
        for (int rt = 0; rt < 4; rt++)
#pragma unroll
            for (int r = 0; r < 4; r++) {
                int row = rt * 16 + ((l >> 4) << 2) + r;
                thr_s[row] = rm[rt][r] + wq_s[row];
            }
    }
    __syncthreads();

    float thr_r[4][4];
#pragma unroll
    for (int rt = 0; rt < 4; rt++)
#pragma unroll
        for (int r = 0; r < 4; r++)
            thr_r[rt][r] = thr_s[rt * 16 + ((l >> 4) << 2) + r];

    // ---- sweep 2: identical arithmetic, collect window candidates ----
    {
        short8v pb0[4], pb1[4];
        PRE_B(0)
        PRE_B(1)
#pragma unroll 4
        for (int ti = 0; ti < 64; ti++) {
            if (ti < 62) PRE_B(ti + 2)
            DOT_TILE(ti, pb0[ti & 3], pb1[ti & 3], ACT_COLLECT)
        }
    }
    __syncthreads();

    // ---- exact rescore (reference-bit-exact chain); lane w == row w ----
    const int nc = cnt_s[l];
    float bv = INFINITY;
    int bi = 0;
    if (nc <= CAP) {
        for (int j = 0; j < nc; j++) {
            const int k = cand_s[l][j];
            const float4* er = (const float4*)(emb + (size_t)k * 64);
            float dot = 0.0f;
#pragma unroll
            for (int q = 0; q < 16; q++) {
                float4 e4 = er[q];
                dot = __builtin_fmaf(zt[l][4 * q + 0], e4.x, dot);
                dot = __builtin_fmaf(zt[l][4 * q + 1], e4.y, dot);
                dot = __builtin_fmaf(zt[l][4 * q + 2], e4.z, dot);
                dot = __builtin_fmaf(zt[l][4 * q + 3], e4.w, dot);
            }
            float tt = zz + ee[k];
            float dv = tt - 2.0f * dot;
            if (dv < bv || (dv == bv && k < bi)) { bv = dv; bi = k; }
        }
    }
    // rare overflow rows: whole-wave exact scan (lex-min == first-min)
    unsigned long long ovf = __ballot(nc > CAP);
    while (ovf) {
        int row = __ffsll(ovf) - 1;
        ovf &= (ovf - 1);
        const float zzr = zz_s[row];
        float lbv = INFINITY;
        int lbi = 0;
        for (int c = 0; c < 16; c++) {
            const int k = c * 64 + l;  // ascending within lane
            const float4* er = (const float4*)(emb + (size_t)k * 64);
            float dot = 0.0f;
#pragma unroll
            for (int q = 0; q < 16; q++) {
                float4 e4 = er[q];
                dot = __builtin_fmaf(zt[row][4 * q + 0], e4.x, dot);
                dot = __builtin_fmaf(zt[row][4 * q + 1], e4.y, dot);
                dot = __builtin_fmaf(zt[row][4 * q + 2], e4.z, dot);
                dot = __builtin_fmaf(zt[row][4 * q + 3], e4.w, dot);
            }
            float tt = zzr + ee[k];
            float dv = tt - 2.0f * dot;
            if (dv < lbv || (dv == lbv && k < lbi)) { lbv = dv; lbi = k; }
        }
#pragma unroll
        for (int off = 1; off < 64; off <<= 1) {
            float ov = __shfl_xor(lbv, off, 64);
            int oi = __shfl_xor(lbi, off, 64);
            if (ov < lbv || (ov == lbv && oi < lbi)) { lbv = ov; lbi = oi; }
        }
        if (l == row) { bv = lbv; bi = lbi; }
    }

    out_idx[n0 + l] = (float)bi;
    atomicAdd(&counts[bi], 1);

    // ---- fused output: quantized gather/store + fp64 loss ----
    const float4* eq = (const float4*)(emb + (size_t)bi * 64);
    float* qb = out_q + (size_t)b * 262144 + (size_t)h * 64;
    double dsum = 0.0;
#pragma unroll 4
    for (int j = 0; j < 16; j++) {
        float4 q4 = eq[j];
        qb[(size_t)(4 * j + 0) * 4096 + l] = q4.x;
        qb[(size_t)(4 * j + 1) * 4096 + l] = q4.y;
        qb[(size_t)(4 * j + 2) * 4096 + l] = q4.z;
        qb[(size_t)(4 * j + 3) * 4096 + l] = q4.w;
        float d0 = q4.x - zt[l][4 * j + 0];
        float d1 = q4.y - zt[l][4 * j + 1];
        float d2 = q4.z - zt[l][4 * j + 2];
        float d3 = q4.w - zt[l][4 * j + 3];
        dsum += (double)(d0 * d0);
        dsum += (double)(d1 * d1);
        dsum += (double)(d2 * d2);
        dsum += (double)(d3 * d3);
    }
    for (int off = 32; off > 0; off >>= 1) dsum += __shfl_down(dsum, off, 64);
    if (l == 0) atomicAdd(loss_sum, dsum);
}

// --- kernel C: loss + perplexity scalars ---
__global__ __launch_bounds__(1024) void kC(const int* __restrict__ counts,
                                           const double* __restrict__ loss_sum,
                                           float* __restrict__ out_loss,
                                           float* __restrict__ out_perp) {
    __shared__ float wr[16];
    const int tid = threadIdx.x;
    float p = (float)counts[tid] * (1.0f / 131072.0f);
    float v = p + 1e-10f;
    float term = p * logf(v);
    float s = term;
    for (int off = 32; off > 0; off >>= 1) s += __shfl_down(s, off, 64);
    if ((tid & 63) == 0) wr[tid >> 6] = s;
    __syncthreads();
    if (tid == 0) {
        float tot = 0.0f;
#pragma unroll
        for (int j = 0; j < 16; j++) tot += wr[j];
        out_perp[0] = expf(-tot);
        double L = *loss_sum / 8388608.0;
        float Lf = (float)L;
        out_loss[0] = Lf + 0.25f * Lf;
    }
}

extern "C" void kernel_launch(void* const* d_in, const int* in_sizes, int n_in,
                              void* d_out, int out_size, void* d_ws, size_t ws_size,
                              hipStream_t stream) {
    const float* z = (const float*)d_in[0];
    const float* emb = (const float*)d_in[1];
    float* out = (float*)d_out;
    float* out_q = out;                    // 8388608
    float* out_loss = out + 8388608;       // 1
    float* out_perp = out + 8388609;       // 1
    float* out_idx = out + 8388610;        // 131072

    char* ws = (char*)d_ws;
    double* loss_sum = (double*)ws;                       // 8 B @ 0
    int* counts = (int*)(ws + 64);                        // 4 KB
    float* ee = (float*)(ws + 64 + 4096);                 // 4 KB
    unsigned short* eh_p = (unsigned short*)(ws + 64 + 8192);  // 128 KB

    hipMemsetAsync(d_ws, 0, 64 + 4096, stream);
    kE<<<4, 256, 0, stream>>>(emb, ee, eh_p);
    kA2<<<2048, 64, 0, stream>>>(z, emb, ee, eh_p, counts, out_idx, out_q,
                                 loss_sum);
    kC<<<1, 1024, 0, stream>>>(counts, loss_sum, out_loss, out_perp);
}